// Round 1
// baseline (466.363 us; speedup 1.0000x reference)
//
#include <hip/hip_runtime.h>

// Flash attention B=2,H=8,N=4096,d=64 fp32 in/out (QKV packed [3,16,4096,64]).
// Round 9: eliminate the P LDS round-trip entirely. The QK^T MFMA's output
// row m equals whichever K row lane m loaded as the A operand, so we permute
// K-row loading with pi(jt,m) = 32*(jt>>1) + 8*(m>>2) + 4*(m&1) + ((m>>1)&1)
// + 2*(jt&1); then each lane's exp2 results, packed in fixed word order, ARE
// the PV A-fragments (kv = 8g+j at lane g). No Ps buffer (36KB LDS freed), no
// transpose shuffles. K tile chunk-XOR-swizzled ((row>>3)&3, both write+read)
// to keep the permuted row reads at uniform 2-way banking. Freed LDS funds a
// K/V double-buffer (one barrier/iter); exp2 fused into the jt loop removes
// the 64-reg S tile (tile0 row-max via one extra QK pass), so launch_bounds
// (256,3) -> 3 blocks/CU; NSPLIT=4 (1024 blocks) fills them. Retained: fp16 K
// prepass + bf16 V^T prepass, static-M (tile0 max + 4 folded into MFMA C),
// split-K with normalized fp16 partials + combine.

typedef _Float16 f16x8 __attribute__((ext_vector_type(8)));
typedef _Float16 f16x2 __attribute__((ext_vector_type(2)));
typedef short s16x8 __attribute__((ext_vector_type(8)));
typedef short s16x4 __attribute__((ext_vector_type(4)));
typedef float f32x4 __attribute__((ext_vector_type(4)));
typedef unsigned u32x4 __attribute__((ext_vector_type(4)));

#define NHEADS 16
#define SEQ 4096
#define HDIM 64
#define BR 256   // Q rows per block (4 waves x 64)
#define NH 4     // 16-row h-tiles per wave
#define BC 64    // KV cols per iteration
#define KP 72    // LDS pitch (halves): 144B rows, 16B-aligned
#define MPAD 4.0f  // M = tile0 row max + MPAD (log2 domain)

__device__ __forceinline__ float fast_exp2(float x) {
#if __has_builtin(__builtin_amdgcn_exp2f)
  return __builtin_amdgcn_exp2f(x);
#else
  return exp2f(x);
#endif
}

__device__ __forceinline__ f16x2 pkrtz(float a, float b) {
  return __builtin_bit_cast(f16x2, __builtin_amdgcn_cvt_pkrtz(a, b));
}

// fp32 -> bf16 RNE (prepass only)
__device__ __forceinline__ unsigned short f2bf(float f) {
  unsigned u = __builtin_bit_cast(unsigned, f);
  u += 0x7fffu + ((u >> 16) & 1u);
  return (unsigned short)(u >> 16);
}

// two fp32 -> two bf16 by truncation (P >= 0; consistent with fp32 psum)
__device__ __forceinline__ unsigned bfpack2(float a, float b) {
  return (__builtin_bit_cast(unsigned, b) & 0xffff0000u) |
         (__builtin_bit_cast(unsigned, a) >> 16);
}

// ---- fused prepass ----
// blocks [0, 2048):  K fp32 -> fp16, layout preserved [16][4096][64]
// blocks [2048, 3072): V fp32 [16][4096][64] -> bf16 transposed [16][64][4096]
__global__ __launch_bounds__(256) void prep(const float* __restrict__ QKV,
                                            _Float16* __restrict__ K16,
                                            short* __restrict__ Vt) {
  const size_t tensElems = (size_t)NHEADS * SEQ * HDIM;
  __shared__ __align__(16) short T[64 * KP];
  if (blockIdx.x < 2048) {
    const float* Kf = QKV + tensElems;
    size_t i = ((size_t)blockIdx.x * 256 + threadIdx.x) * 8;
    float4 a = *(const float4*)(Kf + i);
    float4 b = *(const float4*)(Kf + i + 4);
    union { f16x8 v; f16x2 h2[4]; } u;
    u.h2[0] = pkrtz(a.x, a.y);
    u.h2[1] = pkrtz(a.z, a.w);
    u.h2[2] = pkrtz(b.x, b.y);
    u.h2[3] = pkrtz(b.z, b.w);
    *(f16x8*)(K16 + i) = u.v;
  } else {
    const int vb = blockIdx.x - 2048;
    const int bh = vb >> 6;
    const int nt = vb & 63;
    const float* Vh = QKV + 2 * tensElems + (size_t)bh * SEQ * HDIM +
                      (size_t)nt * 64 * HDIM;
    const int t = threadIdx.x;
    #pragma unroll
    for (int p = 0; p < 4; ++p) {
      int idx = t + p * 256;
      int row = idx >> 4, c4 = (idx & 15) << 2;
      float4 v = *(const float4*)(Vh + row * HDIM + c4);
      s16x4 h;
      h[0] = (short)f2bf(v.x); h[1] = (short)f2bf(v.y);
      h[2] = (short)f2bf(v.z); h[3] = (short)f2bf(v.w);
      *(s16x4*)&T[row * KP + c4] = h;
    }
    __syncthreads();
    const int d = t & 63, w = t >> 6;
    s16x8 o0, o1;
    #pragma unroll
    for (int j = 0; j < 8; ++j) o0[j] = T[(w * 16 + j) * KP + d];
    #pragma unroll
    for (int j = 0; j < 8; ++j) o1[j] = T[(w * 16 + 8 + j) * KP + d];
    short* out = Vt + (size_t)bh * HDIM * SEQ + (size_t)d * SEQ + nt * 64 + w * 16;
    *(s16x8*)out = o0;
    *(s16x8*)(out + 8) = o1;
  }
}

// ---- combine: merge NS normalized fp16 partials ----
template <int NS>
__global__ __launch_bounds__(256) void combineN(const _Float16* __restrict__ Op,
                                                const float2* __restrict__ Ml,
                                                float* __restrict__ O) {
  const size_t tensElems = (size_t)NHEADS * SEQ * HDIM;
  size_t t = (size_t)blockIdx.x * 256 + threadIdx.x;  // 8 elems per thread
  size_t row = t >> 3;
  int seg = (int)(t & 7) << 3;
  float2 s[NS];
  #pragma unroll
  for (int i = 0; i < NS; ++i) s[i] = Ml[(size_t)i * NHEADS * SEQ + row];
  float Ms = s[0].x;
  #pragma unroll
  for (int i = 1; i < NS; ++i) Ms = fmaxf(Ms, s[i].x);
  float a[NS], tot = 0.f;
  #pragma unroll
  for (int i = 0; i < NS; ++i) {
    a[i] = fast_exp2(s[i].x - Ms) * s[i].y;
    tot += a[i];
  }
  float inv = 1.0f / tot;
  float r[8] = {0.f, 0.f, 0.f, 0.f, 0.f, 0.f, 0.f, 0.f};
  #pragma unroll
  for (int i = 0; i < NS; ++i) {
    f16x8 o = *(const f16x8*)(Op + (size_t)i * tensElems + row * HDIM + seg);
    float w = a[i] * inv;
    #pragma unroll
    for (int j = 0; j < 8; ++j) r[j] += (float)o[j] * w;
  }
  float4 r0{r[0], r[1], r[2], r[3]}, r1{r[4], r[5], r[6], r[7]};
  *(float4*)(O + row * HDIM + seg) = r0;
  *(float4*)(O + row * HDIM + seg + 4) = r1;
}

// ---- main kernel ----
template <bool PRE, bool SPLIT>
__global__ __launch_bounds__(256, 3) void flash_attn(const float* __restrict__ QKV,
                                                     const _Float16* __restrict__ K16g,
                                                     const short* __restrict__ Vt16,
                                                     float* __restrict__ Out,
                                                     _Float16* __restrict__ Opart,
                                                     float2* __restrict__ Ml) {
  const size_t headElems = (size_t)SEQ * HDIM;
  const size_t tensElems = (size_t)NHEADS * headElems;
  const int bh = blockIdx.x & 15;   // same-bh blocks 16 apart -> same XCD
  const int qt = blockIdx.x >> 4;   // 0..15
  const int split = SPLIT ? blockIdx.y : 0;
  const int nsp = SPLIT ? (int)gridDim.y : 1;
  const int ktN = (SEQ / BC) / nsp;
  const int ktBeg = split * ktN;

  const float* Q = QKV + (size_t)bh * headElems;
  const float* Kf = QKV + tensElems + (size_t)bh * headElems;
  const float* Vf = QKV + 2 * tensElems + (size_t)bh * headElems;
  const _Float16* Kg16 = K16g + (size_t)bh * headElems;  // [n][d] fp16
  const short* Vg16 = Vt16 + (size_t)bh * headElems;     // [d][n] bf16
  float* O = Out + (size_t)bh * headElems;

  const int tid = threadIdx.x;
  const int wave = tid >> 6;
  const int lane = tid & 63;
  const int g = lane >> 4;
  const int l16 = lane & 15;

  // double-buffered tiles: 2 * (9216 + 9216) = 36864 B
  __shared__ __align__(16) _Float16 KsB[2][BC * KP];  // [kv][d] fp16, chunk-swizzled
  __shared__ __align__(16) short VsB[2][HDIM * KP];   // [d][kv] bf16

  // ---- Q fragments (B operand of S^T): lane l16 = Q row, k = g*8+j ----
  const float LOG2E = 1.4426950408889634f;
  const int qbase = qt * BR + wave * (16 * NH);
  f16x8 qf[NH][2];
  #pragma unroll
  for (int h = 0; h < NH; ++h) {
    const float* qp = Q + (size_t)(qbase + h * 16 + l16) * HDIM + g * 8;
    #pragma unroll
    for (int c = 0; c < 2; ++c) {
      float4 a = *(const float4*)(qp + c * 32);
      float4 b = *(const float4*)(qp + c * 32 + 4);
      union { f16x8 v; f16x2 h2[4]; } u;
      u.h2[0] = pkrtz(a.x * LOG2E, a.y * LOG2E);
      u.h2[1] = pkrtz(a.z * LOG2E, a.w * LOG2E);
      u.h2[2] = pkrtz(b.x * LOG2E, b.y * LOG2E);
      u.h2[3] = pkrtz(b.z * LOG2E, b.w * LOG2E);
      qf[h][c] = u.v;
    }
  }

  // pi-addressing lane constants: QK A-operand row for mfma jt at lane l16 is
  //   row = rbase + 32*(jt>>1) + 2*(jt&1),
  // which makes S^T output slot (jt,ri) at lane g hold exactly kv = 8g+j with
  // j = 4*(ri&1) + (ri>>1) + 2*(jt&1), half = jt>>1  (PV A-fragment layout).
  const int rbase = 8 * (l16 >> 2) + 4 * (l16 & 1) + ((l16 >> 1) & 1);
  // chunk-XOR swizzle: 16B chunk c of row r lives at chunk c ^ ((r>>3)&3).
  // For the frag read, (row>>3)&3 == l16>>2 for every jt.
  const int swz = ((g ^ (l16 >> 2)) << 3);  // halves offset of swizzled chunk g

  const int sr = tid >> 2;          // staged row 0..63
  const int sc = (tid & 3) << 4;    // staged col (halves) 0,16,32,48
  const int qw = (sr >> 3) & 3;     // write-side swizzle key
  const int kc0 = ((((tid & 3) << 1) + 0) ^ qw) << 3;  // swizzled half-offsets
  const int kc1 = ((((tid & 3) << 1) + 1) ^ qw) << 3;

  s16x8 kpre[2];   // fp16 bits held as shorts
  s16x8 vpre[2];

  auto prefetch = [&](int kt) {
    if constexpr (PRE) {
      const _Float16* kg = Kg16 + (size_t)(kt * BC + sr) * HDIM + sc;
      kpre[0] = *(const s16x8*)(kg);
      kpre[1] = *(const s16x8*)(kg + 8);
      const short* vg = Vg16 + (size_t)sr * SEQ + kt * BC + sc;
      vpre[0] = *(const s16x8*)(vg);
      vpre[1] = *(const s16x8*)(vg + 8);
    }
  };
  auto commit = [&](int buf, int kt) {
    _Float16* Kd = KsB[buf];
    short* Vd = VsB[buf];
    if constexpr (PRE) {
      *(s16x8*)&Kd[sr * KP + kc0] = kpre[0];
      *(s16x8*)&Kd[sr * KP + kc1] = kpre[1];
      *(s16x8*)&Vd[sr * KP + sc] = vpre[0];
      *(s16x8*)&Vd[sr * KP + sc + 8] = vpre[1];
    } else {
      const float* kg = Kf + (size_t)(kt * BC + sr) * HDIM + sc;
      float4 a = *(const float4*)(kg), b = *(const float4*)(kg + 4);
      float4 c = *(const float4*)(kg + 8), d = *(const float4*)(kg + 12);
      union { f16x8 v; f16x2 h2[4]; } ka, kb;
      ka.h2[0] = pkrtz(a.x, a.y);
      ka.h2[1] = pkrtz(a.z, a.w);
      ka.h2[2] = pkrtz(b.x, b.y);
      ka.h2[3] = pkrtz(b.z, b.w);
      kb.h2[0] = pkrtz(c.x, c.y);
      kb.h2[1] = pkrtz(c.z, c.w);
      kb.h2[2] = pkrtz(d.x, d.y);
      kb.h2[3] = pkrtz(d.z, d.w);
      *(f16x8*)&Kd[sr * KP + kc0] = ka.v;
      *(f16x8*)&Kd[sr * KP + kc1] = kb.v;
      const float* vg = Vf + (size_t)(kt * BC + sr) * HDIM + sc;
      float4 va = *(const float4*)(vg), vb = *(const float4*)(vg + 4);
      float4 vc = *(const float4*)(vg + 8), vd = *(const float4*)(vg + 12);
      float vv[16] = {va.x, va.y, va.z, va.w, vb.x, vb.y, vb.z, vb.w,
                      vc.x, vc.y, vc.z, vc.w, vd.x, vd.y, vd.z, vd.w};
      #pragma unroll
      for (int j = 0; j < 16; ++j) Vd[(sc + j) * KP + sr] = (short)f2bf(vv[j]);
    }
  };

  f32x4 acc[NH][4];
  #pragma unroll
  for (int h = 0; h < NH; ++h)
    #pragma unroll
    for (int nt = 0; nt < 4; ++nt)
      #pragma unroll
      for (int i = 0; i < 4; ++i) acc[h][nt][i] = 0.f;
  float l_[NH] = {0.f, 0.f, 0.f, 0.f};
  float negM[NH] = {0.f, 0.f, 0.f, 0.f};

  prefetch(ktBeg);
  commit(0, ktBeg);
  int cur = 0;

  for (int it = 0; it < ktN; ++it) {
    __syncthreads();            // buf[cur] staged; buf[cur^1] free to overwrite
    if (it + 1 < ktN) prefetch(ktBeg + it + 1);
    const _Float16* Kb = KsB[cur];
    const short* Vb = VsB[cur];

    // ---- tile 0 only: cheap extra QK pass to derive per-row static M ----
    if (it == 0) {
      float mx[NH];
      #pragma unroll
      for (int h = 0; h < NH; ++h) mx[h] = -3.0e38f;
      #pragma unroll
      for (int jt = 0; jt < 4; ++jt) {
        const int ka = (rbase + ((jt >> 1) << 5) + ((jt & 1) << 1)) * KP + swz;
        f16x8 k0 = *(const f16x8*)&Kb[ka];
        f16x8 k1 = *(const f16x8*)&Kb[ka + 32];
        #pragma unroll
        for (int h = 0; h < NH; ++h) {
          f32x4 z;
          z[0] = z[1] = z[2] = z[3] = 0.f;
          z = __builtin_amdgcn_mfma_f32_16x16x32_f16(k0, qf[h][0], z, 0, 0, 0);
          z = __builtin_amdgcn_mfma_f32_16x16x32_f16(k1, qf[h][1], z, 0, 0, 0);
          mx[h] = fmaxf(mx[h], fmaxf(fmaxf(z[0], z[1]), fmaxf(z[2], z[3])));
        }
      }
      #pragma unroll
      for (int h = 0; h < NH; ++h) {
        float m2 = fmaxf(mx[h], __shfl_xor(mx[h], 16));
        m2 = fmaxf(m2, __shfl_xor(m2, 32));
        negM[h] = -(m2 + MPAD);
      }
    }

    // ---- S^T - M (pi-permuted rows), exp2 fused, packed straight into the
    //      PV A-fragments: pa[half] word order {jtE(ri0,ri2), jtO(ri0,ri2),
    //      jtE(ri1,ri3), jtO(ri1,ri3)} with jtE=2*half, jtO=2*half+1 ----
    u32x4 Wp[NH][2];
    #pragma unroll
    for (int jt = 0; jt < 4; ++jt) {
      const int ka = (rbase + ((jt >> 1) << 5) + ((jt & 1) << 1)) * KP + swz;
      f16x8 k0 = *(const f16x8*)&Kb[ka];
      f16x8 k1 = *(const f16x8*)&Kb[ka + 32];
      #pragma unroll
      for (int h = 0; h < NH; ++h) {
        f32x4 z;
        z[0] = z[1] = z[2] = z[3] = negM[h];   // -M folded into C
        z = __builtin_amdgcn_mfma_f32_16x16x32_f16(k0, qf[h][0], z, 0, 0, 0);
        z = __builtin_amdgcn_mfma_f32_16x16x32_f16(k1, qf[h][1], z, 0, 0, 0);
        float p0 = fast_exp2(z[0]);
        float p1 = fast_exp2(z[1]);
        float p2 = fast_exp2(z[2]);
        float p3 = fast_exp2(z[3]);
        l_[h] += (p0 + p1) + (p2 + p3);
        Wp[h][jt >> 1][(jt & 1)] = bfpack2(p0, p2);
        Wp[h][jt >> 1][(jt & 1) + 2] = bfpack2(p1, p3);
      }
    }

    // ---- O += P V  (A = in-register P bf16, B = V^T bf16) ----
    #pragma unroll
    for (int nt = 0; nt < 4; ++nt) {
      const int va = (nt * 16 + l16) * KP + g * 8;
      s16x8 v0 = *(const s16x8*)&Vb[va];
      s16x8 v1 = *(const s16x8*)&Vb[va + 32];
      #pragma unroll
      for (int h = 0; h < NH; ++h) {
        s16x8 pa0 = __builtin_bit_cast(s16x8, Wp[h][0]);
        s16x8 pa1 = __builtin_bit_cast(s16x8, Wp[h][1]);
        acc[h][nt] = __builtin_amdgcn_mfma_f32_16x16x32_bf16(pa0, v0, acc[h][nt], 0, 0, 0);
        acc[h][nt] = __builtin_amdgcn_mfma_f32_16x16x32_bf16(pa1, v1, acc[h][nt], 0, 0, 0);
      }
    }

    if (it + 1 < ktN) commit(cur ^ 1, ktBeg + it + 1);
    cur ^= 1;
  }

  // ---- epilogue ----
  #pragma unroll
  for (int h = 0; h < NH; ++h) {
    float lf = l_[h];
    lf += __shfl_xor(lf, 16);
    lf += __shfl_xor(lf, 32);
    float linv = 1.0f / lf;
    if constexpr (SPLIT) {
      if (g == 0) {
        Ml[(size_t)split * NHEADS * SEQ + (size_t)bh * SEQ + qbase + h * 16 + l16] =
            float2{-negM[h], lf};
      }
      _Float16* op = Opart + (size_t)split * tensElems + (size_t)bh * headElems;
      #pragma unroll
      for (int ri = 0; ri < 4; ++ri) {
        float lB = __shfl(linv, 4 * g + ri);
        const int row = qbase + h * 16 + 4 * g + ri;
        #pragma unroll
        for (int nt = 0; nt < 4; ++nt)
          op[(size_t)row * HDIM + nt * 16 + l16] = (_Float16)(acc[h][nt][ri] * lB);
      }
    } else {
      #pragma unroll
      for (int ri = 0; ri < 4; ++ri) {
        float lB = __shfl(linv, 4 * g + ri);
        const int row = qbase + h * 16 + 4 * g + ri;
        #pragma unroll
        for (int nt = 0; nt < 4; ++nt)
          O[(size_t)row * HDIM + nt * 16 + l16] = acc[h][nt][ri] * lB;
      }
    }
  }
}

extern "C" void kernel_launch(void* const* d_in, const int* in_sizes, int n_in,
                              void* d_out, int out_size, void* d_ws, size_t ws_size,
                              hipStream_t stream) {
  const float* QKV = (const float*)d_in[0];
  float* Out = (float*)d_out;
  const size_t tensElems = (size_t)NHEADS * SEQ * HDIM;             // 4,194,304
  const size_t k16Bytes = tensElems * sizeof(_Float16);             // 8.39 MB
  const size_t vtBytes = tensElems * sizeof(short);                 // 8.39 MB
  const size_t mlUnit = (size_t)NHEADS * SEQ * sizeof(float2);      // 0.52 MB
  const size_t need4 = k16Bytes + vtBytes + 4 * tensElems * 2 + 4 * mlUnit;  // 52.4 MB
  const size_t need2 = k16Bytes + vtBytes + 2 * tensElems * 2 + 2 * mlUnit;  // 34.6 MB

  dim3 block(256);
  _Float16* K16 = (_Float16*)d_ws;
  short* Vt16 = (short*)((char*)d_ws + k16Bytes);
  char* rest = (char*)d_ws + k16Bytes + vtBytes;

  if (ws_size >= need4) {
    _Float16* Opart = (_Float16*)rest;
    float2* Ml = (float2*)(rest + 4 * tensElems * 2);
    hipLaunchKernelGGL(prep, dim3(3072), block, 0, stream, QKV, K16, Vt16);
    hipLaunchKernelGGL((flash_attn<true, true>), dim3(NHEADS * (SEQ / BR), 4),
                       block, 0, stream, QKV, K16, Vt16, Out, Opart, Ml);
    hipLaunchKernelGGL((combineN<4>), dim3((NHEADS * SEQ * HDIM / 8) / 256), block,
                       0, stream, Opart, Ml, Out);
  } else if (ws_size >= need2) {
    _Float16* Opart = (_Float16*)rest;
    float2* Ml = (float2*)(rest + 2 * tensElems * 2);
    hipLaunchKernelGGL(prep, dim3(3072), block, 0, stream, QKV, K16, Vt16);
    hipLaunchKernelGGL((flash_attn<true, true>), dim3(NHEADS * (SEQ / BR), 2),
                       block, 0, stream, QKV, K16, Vt16, Out, Opart, Ml);
    hipLaunchKernelGGL((combineN<2>), dim3((NHEADS * SEQ * HDIM / 8) / 256), block,
                       0, stream, Opart, Ml, Out);
  } else {
    hipLaunchKernelGGL((flash_attn<false, false>), dim3(NHEADS * (SEQ / BR)), block,
                       0, stream, QKV, (const _Float16*)nullptr,
                       (const short*)nullptr, Out, (_Float16*)nullptr,
                       (float2*)nullptr);
  }
}

// Round 2
// 161.305 us; speedup vs baseline: 2.8912x; 2.8912x over previous
//
#include <hip/hip_runtime.h>

// Flash attention B=2,H=8,N=4096,d=64 fp32 in/out (QKV packed [3,16,4096,64]).
// Round 10: round 9's pi-permutation structure (in-register P; no Ps LDS
// buffer; K/V double-buffer, one barrier/iter) with the spill fixed. Round 9
// forced __launch_bounds__(256,3) -> 170-VGPR cap -> accumulator spill to
// scratch (FETCH 539MB, WRITE 818MB, 403us). Now (256,2): 256-VGPR budget;
// if natural use lands <=170 HW gives 3 blocks/CU anyway (LDS 36.8KB allows
// 4). NSPLIT back to 2 (512 blocks = full residency at 2/CU, half the
// combine traffic, tile0-max amortized over 32 iters).
// Retained: pi(jt,m) K-row permutation so each lane's exp2 outputs ARE the
// PV A-fragments (kv=8g+j at lane g); chunk-XOR swizzle ((row>>3)&3) on K
// commit-write + frag-read; fp16 K prepass + bf16 V^T prepass; static-M
// (tile0 max + MPAD folded into MFMA C); split-K normalized fp16 partials.

typedef _Float16 f16x8 __attribute__((ext_vector_type(8)));
typedef _Float16 f16x2 __attribute__((ext_vector_type(2)));
typedef short s16x8 __attribute__((ext_vector_type(8)));
typedef short s16x4 __attribute__((ext_vector_type(4)));
typedef float f32x4 __attribute__((ext_vector_type(4)));
typedef unsigned u32x4 __attribute__((ext_vector_type(4)));

#define NHEADS 16
#define SEQ 4096
#define HDIM 64
#define BR 256   // Q rows per block (4 waves x 64)
#define NH 4     // 16-row h-tiles per wave
#define BC 64    // KV cols per iteration
#define KP 72    // LDS pitch (halves): 144B rows, 16B-aligned
#define NSPLIT 2
#define MPAD 4.0f  // M = tile0 row max + MPAD (log2 domain)

__device__ __forceinline__ float fast_exp2(float x) {
#if __has_builtin(__builtin_amdgcn_exp2f)
  return __builtin_amdgcn_exp2f(x);
#else
  return exp2f(x);
#endif
}

__device__ __forceinline__ f16x2 pkrtz(float a, float b) {
  return __builtin_bit_cast(f16x2, __builtin_amdgcn_cvt_pkrtz(a, b));
}

// fp32 -> bf16 RNE (prepass only)
__device__ __forceinline__ unsigned short f2bf(float f) {
  unsigned u = __builtin_bit_cast(unsigned, f);
  u += 0x7fffu + ((u >> 16) & 1u);
  return (unsigned short)(u >> 16);
}

// two fp32 -> two bf16 by truncation (P >= 0; consistent with fp32 psum)
__device__ __forceinline__ unsigned bfpack2(float a, float b) {
  return (__builtin_bit_cast(unsigned, b) & 0xffff0000u) |
         (__builtin_bit_cast(unsigned, a) >> 16);
}

// ---- fused prepass ----
// blocks [0, 2048):  K fp32 -> fp16, layout preserved [16][4096][64]
// blocks [2048, 3072): V fp32 [16][4096][64] -> bf16 transposed [16][64][4096]
__global__ __launch_bounds__(256) void prep(const float* __restrict__ QKV,
                                            _Float16* __restrict__ K16,
                                            short* __restrict__ Vt) {
  const size_t tensElems = (size_t)NHEADS * SEQ * HDIM;
  __shared__ __align__(16) short T[64 * KP];
  if (blockIdx.x < 2048) {
    const float* Kf = QKV + tensElems;
    size_t i = ((size_t)blockIdx.x * 256 + threadIdx.x) * 8;
    float4 a = *(const float4*)(Kf + i);
    float4 b = *(const float4*)(Kf + i + 4);
    union { f16x8 v; f16x2 h2[4]; } u;
    u.h2[0] = pkrtz(a.x, a.y);
    u.h2[1] = pkrtz(a.z, a.w);
    u.h2[2] = pkrtz(b.x, b.y);
    u.h2[3] = pkrtz(b.z, b.w);
    *(f16x8*)(K16 + i) = u.v;
  } else {
    const int vb = blockIdx.x - 2048;
    const int bh = vb >> 6;
    const int nt = vb & 63;
    const float* Vh = QKV + 2 * tensElems + (size_t)bh * SEQ * HDIM +
                      (size_t)nt * 64 * HDIM;
    const int t = threadIdx.x;
    #pragma unroll
    for (int p = 0; p < 4; ++p) {
      int idx = t + p * 256;
      int row = idx >> 4, c4 = (idx & 15) << 2;
      float4 v = *(const float4*)(Vh + row * HDIM + c4);
      s16x4 h;
      h[0] = (short)f2bf(v.x); h[1] = (short)f2bf(v.y);
      h[2] = (short)f2bf(v.z); h[3] = (short)f2bf(v.w);
      *(s16x4*)&T[row * KP + c4] = h;
    }
    __syncthreads();
    const int d = t & 63, w = t >> 6;
    s16x8 o0, o1;
    #pragma unroll
    for (int j = 0; j < 8; ++j) o0[j] = T[(w * 16 + j) * KP + d];
    #pragma unroll
    for (int j = 0; j < 8; ++j) o1[j] = T[(w * 16 + 8 + j) * KP + d];
    short* out = Vt + (size_t)bh * HDIM * SEQ + (size_t)d * SEQ + nt * 64 + w * 16;
    *(s16x8*)out = o0;
    *(s16x8*)(out + 8) = o1;
  }
}

// ---- combine: merge NS normalized fp16 partials ----
template <int NS>
__global__ __launch_bounds__(256) void combineN(const _Float16* __restrict__ Op,
                                                const float2* __restrict__ Ml,
                                                float* __restrict__ O) {
  const size_t tensElems = (size_t)NHEADS * SEQ * HDIM;
  size_t t = (size_t)blockIdx.x * 256 + threadIdx.x;  // 8 elems per thread
  size_t row = t >> 3;
  int seg = (int)(t & 7) << 3;
  float2 s[NS];
  #pragma unroll
  for (int i = 0; i < NS; ++i) s[i] = Ml[(size_t)i * NHEADS * SEQ + row];
  float Ms = s[0].x;
  #pragma unroll
  for (int i = 1; i < NS; ++i) Ms = fmaxf(Ms, s[i].x);
  float a[NS], tot = 0.f;
  #pragma unroll
  for (int i = 0; i < NS; ++i) {
    a[i] = fast_exp2(s[i].x - Ms) * s[i].y;
    tot += a[i];
  }
  float inv = 1.0f / tot;
  float r[8] = {0.f, 0.f, 0.f, 0.f, 0.f, 0.f, 0.f, 0.f};
  #pragma unroll
  for (int i = 0; i < NS; ++i) {
    f16x8 o = *(const f16x8*)(Op + (size_t)i * tensElems + row * HDIM + seg);
    float w = a[i] * inv;
    #pragma unroll
    for (int j = 0; j < 8; ++j) r[j] += (float)o[j] * w;
  }
  float4 r0{r[0], r[1], r[2], r[3]}, r1{r[4], r[5], r[6], r[7]};
  *(float4*)(O + row * HDIM + seg) = r0;
  *(float4*)(O + row * HDIM + seg + 4) = r1;
}

// ---- main kernel ----
template <bool PRE, bool SPLIT>
__global__ __launch_bounds__(256, 2) void flash_attn(const float* __restrict__ QKV,
                                                     const _Float16* __restrict__ K16g,
                                                     const short* __restrict__ Vt16,
                                                     float* __restrict__ Out,
                                                     _Float16* __restrict__ Opart,
                                                     float2* __restrict__ Ml) {
  const size_t headElems = (size_t)SEQ * HDIM;
  const size_t tensElems = (size_t)NHEADS * headElems;
  const int bh = blockIdx.x & 15;   // same-bh blocks 16 apart -> same XCD
  const int qt = blockIdx.x >> 4;   // 0..15
  const int split = SPLIT ? blockIdx.y : 0;
  const int nsp = SPLIT ? (int)gridDim.y : 1;
  const int ktN = (SEQ / BC) / nsp;
  const int ktBeg = split * ktN;

  const float* Q = QKV + (size_t)bh * headElems;
  const float* Kf = QKV + tensElems + (size_t)bh * headElems;
  const float* Vf = QKV + 2 * tensElems + (size_t)bh * headElems;
  const _Float16* Kg16 = K16g + (size_t)bh * headElems;  // [n][d] fp16
  const short* Vg16 = Vt16 + (size_t)bh * headElems;     // [d][n] bf16
  float* O = Out + (size_t)bh * headElems;

  const int tid = threadIdx.x;
  const int wave = tid >> 6;
  const int lane = tid & 63;
  const int g = lane >> 4;
  const int l16 = lane & 15;

  // double-buffered tiles: 2 * (9216 + 9216) = 36864 B
  __shared__ __align__(16) _Float16 KsB[2][BC * KP];  // [kv][d] fp16, chunk-swizzled
  __shared__ __align__(16) short VsB[2][HDIM * KP];   // [d][kv] bf16

  // ---- Q fragments (B operand of S^T): lane l16 = Q row, k = g*8+j ----
  const float LOG2E = 1.4426950408889634f;
  const int qbase = qt * BR + wave * (16 * NH);
  f16x8 qf[NH][2];
  #pragma unroll
  for (int h = 0; h < NH; ++h) {
    const float* qp = Q + (size_t)(qbase + h * 16 + l16) * HDIM + g * 8;
    #pragma unroll
    for (int c = 0; c < 2; ++c) {
      float4 a = *(const float4*)(qp + c * 32);
      float4 b = *(const float4*)(qp + c * 32 + 4);
      union { f16x8 v; f16x2 h2[4]; } u;
      u.h2[0] = pkrtz(a.x * LOG2E, a.y * LOG2E);
      u.h2[1] = pkrtz(a.z * LOG2E, a.w * LOG2E);
      u.h2[2] = pkrtz(b.x * LOG2E, b.y * LOG2E);
      u.h2[3] = pkrtz(b.z * LOG2E, b.w * LOG2E);
      qf[h][c] = u.v;
    }
  }

  // pi-addressing lane constants: QK A-operand row for mfma jt at lane l16 is
  //   row = rbase + 32*(jt>>1) + 2*(jt&1),
  // which makes S^T output slot (jt,ri) at lane g hold exactly kv = 8g+j with
  // j = 4*(ri&1) + (ri>>1) + 2*(jt&1), half = jt>>1  (PV A-fragment layout).
  const int rbase = 8 * (l16 >> 2) + 4 * (l16 & 1) + ((l16 >> 1) & 1);
  // chunk-XOR swizzle: 16B chunk c of row r lives at chunk c ^ ((r>>3)&3).
  // For the frag read, (row>>3)&3 == l16>>2 for every jt.
  const int swz = ((g ^ (l16 >> 2)) << 3);  // halves offset of swizzled chunk g

  const int sr = tid >> 2;          // staged row 0..63
  const int sc = (tid & 3) << 4;    // staged col (halves) 0,16,32,48
  const int qw = (sr >> 3) & 3;     // write-side swizzle key
  const int kc0 = ((((tid & 3) << 1) + 0) ^ qw) << 3;  // swizzled half-offsets
  const int kc1 = ((((tid & 3) << 1) + 1) ^ qw) << 3;

  s16x8 kpre[2];   // fp16 bits held as shorts
  s16x8 vpre[2];

  auto prefetch = [&](int kt) {
    if constexpr (PRE) {
      const _Float16* kg = Kg16 + (size_t)(kt * BC + sr) * HDIM + sc;
      kpre[0] = *(const s16x8*)(kg);
      kpre[1] = *(const s16x8*)(kg + 8);
      const short* vg = Vg16 + (size_t)sr * SEQ + kt * BC + sc;
      vpre[0] = *(const s16x8*)(vg);
      vpre[1] = *(const s16x8*)(vg + 8);
    }
  };
  auto commit = [&](int buf, int kt) {
    _Float16* Kd = KsB[buf];
    short* Vd = VsB[buf];
    if constexpr (PRE) {
      *(s16x8*)&Kd[sr * KP + kc0] = kpre[0];
      *(s16x8*)&Kd[sr * KP + kc1] = kpre[1];
      *(s16x8*)&Vd[sr * KP + sc] = vpre[0];
      *(s16x8*)&Vd[sr * KP + sc + 8] = vpre[1];
    } else {
      const float* kg = Kf + (size_t)(kt * BC + sr) * HDIM + sc;
      float4 a = *(const float4*)(kg), b = *(const float4*)(kg + 4);
      float4 c = *(const float4*)(kg + 8), d = *(const float4*)(kg + 12);
      union { f16x8 v; f16x2 h2[4]; } ka, kb;
      ka.h2[0] = pkrtz(a.x, a.y);
      ka.h2[1] = pkrtz(a.z, a.w);
      ka.h2[2] = pkrtz(b.x, b.y);
      ka.h2[3] = pkrtz(b.z, b.w);
      kb.h2[0] = pkrtz(c.x, c.y);
      kb.h2[1] = pkrtz(c.z, c.w);
      kb.h2[2] = pkrtz(d.x, d.y);
      kb.h2[3] = pkrtz(d.z, d.w);
      *(f16x8*)&Kd[sr * KP + kc0] = ka.v;
      *(f16x8*)&Kd[sr * KP + kc1] = kb.v;
      const float* vg = Vf + (size_t)(kt * BC + sr) * HDIM + sc;
      float4 va = *(const float4*)(vg), vb = *(const float4*)(vg + 4);
      float4 vc = *(const float4*)(vg + 8), vd = *(const float4*)(vg + 12);
      float vv[16] = {va.x, va.y, va.z, va.w, vb.x, vb.y, vb.z, vb.w,
                      vc.x, vc.y, vc.z, vc.w, vd.x, vd.y, vd.z, vd.w};
      #pragma unroll
      for (int j = 0; j < 16; ++j) Vd[(sc + j) * KP + sr] = (short)f2bf(vv[j]);
    }
  };

  f32x4 acc[NH][4];
  #pragma unroll
  for (int h = 0; h < NH; ++h)
    #pragma unroll
    for (int nt = 0; nt < 4; ++nt)
      #pragma unroll
      for (int i = 0; i < 4; ++i) acc[h][nt][i] = 0.f;
  float l_[NH] = {0.f, 0.f, 0.f, 0.f};
  float negM[NH] = {0.f, 0.f, 0.f, 0.f};

  prefetch(ktBeg);
  commit(0, ktBeg);
  int cur = 0;

  for (int it = 0; it < ktN; ++it) {
    __syncthreads();            // buf[cur] staged; buf[cur^1] free to overwrite
    if (it + 1 < ktN) prefetch(ktBeg + it + 1);
    const _Float16* Kb = KsB[cur];
    const short* Vb = VsB[cur];

    // ---- tile 0 only: cheap extra QK pass to derive per-row static M ----
    if (it == 0) {
      float mx[NH];
      #pragma unroll
      for (int h = 0; h < NH; ++h) mx[h] = -3.0e38f;
      #pragma unroll
      for (int jt = 0; jt < 4; ++jt) {
        const int ka = (rbase + ((jt >> 1) << 5) + ((jt & 1) << 1)) * KP + swz;
        f16x8 k0 = *(const f16x8*)&Kb[ka];
        f16x8 k1 = *(const f16x8*)&Kb[ka + 32];
        #pragma unroll
        for (int h = 0; h < NH; ++h) {
          f32x4 z;
          z[0] = z[1] = z[2] = z[3] = 0.f;
          z = __builtin_amdgcn_mfma_f32_16x16x32_f16(k0, qf[h][0], z, 0, 0, 0);
          z = __builtin_amdgcn_mfma_f32_16x16x32_f16(k1, qf[h][1], z, 0, 0, 0);
          mx[h] = fmaxf(mx[h], fmaxf(fmaxf(z[0], z[1]), fmaxf(z[2], z[3])));
        }
      }
      #pragma unroll
      for (int h = 0; h < NH; ++h) {
        float m2 = fmaxf(mx[h], __shfl_xor(mx[h], 16));
        m2 = fmaxf(m2, __shfl_xor(m2, 32));
        negM[h] = -(m2 + MPAD);
      }
    }

    // ---- S^T - M (pi-permuted rows), exp2 fused, packed straight into the
    //      PV A-fragments: pa[half] word order {jtE(ri0,ri2), jtO(ri0,ri2),
    //      jtE(ri1,ri3), jtO(ri1,ri3)} with jtE=2*half, jtO=2*half+1 ----
    u32x4 Wp[NH][2];
    #pragma unroll
    for (int jt = 0; jt < 4; ++jt) {
      const int ka = (rbase + ((jt >> 1) << 5) + ((jt & 1) << 1)) * KP + swz;
      f16x8 k0 = *(const f16x8*)&Kb[ka];
      f16x8 k1 = *(const f16x8*)&Kb[ka + 32];
      #pragma unroll
      for (int h = 0; h < NH; ++h) {
        f32x4 z;
        z[0] = z[1] = z[2] = z[3] = negM[h];   // -M folded into C
        z = __builtin_amdgcn_mfma_f32_16x16x32_f16(k0, qf[h][0], z, 0, 0, 0);
        z = __builtin_amdgcn_mfma_f32_16x16x32_f16(k1, qf[h][1], z, 0, 0, 0);
        float p0 = fast_exp2(z[0]);
        float p1 = fast_exp2(z[1]);
        float p2 = fast_exp2(z[2]);
        float p3 = fast_exp2(z[3]);
        l_[h] += (p0 + p1) + (p2 + p3);
        Wp[h][jt >> 1][(jt & 1)] = bfpack2(p0, p2);
        Wp[h][jt >> 1][(jt & 1) + 2] = bfpack2(p1, p3);
      }
    }

    // ---- O += P V  (A = in-register P bf16, B = V^T bf16) ----
    #pragma unroll
    for (int nt = 0; nt < 4; ++nt) {
      const int va = (nt * 16 + l16) * KP + g * 8;
      s16x8 v0 = *(const s16x8*)&Vb[va];
      s16x8 v1 = *(const s16x8*)&Vb[va + 32];
      #pragma unroll
      for (int h = 0; h < NH; ++h) {
        s16x8 pa0 = __builtin_bit_cast(s16x8, Wp[h][0]);
        s16x8 pa1 = __builtin_bit_cast(s16x8, Wp[h][1]);
        acc[h][nt] = __builtin_amdgcn_mfma_f32_16x16x32_bf16(pa0, v0, acc[h][nt], 0, 0, 0);
        acc[h][nt] = __builtin_amdgcn_mfma_f32_16x16x32_bf16(pa1, v1, acc[h][nt], 0, 0, 0);
      }
    }

    if (it + 1 < ktN) commit(cur ^ 1, ktBeg + it + 1);
    cur ^= 1;
  }

  // ---- epilogue ----
  #pragma unroll
  for (int h = 0; h < NH; ++h) {
    float lf = l_[h];
    lf += __shfl_xor(lf, 16);
    lf += __shfl_xor(lf, 32);
    float linv = 1.0f / lf;
    if constexpr (SPLIT) {
      if (g == 0) {
        Ml[(size_t)split * NHEADS * SEQ + (size_t)bh * SEQ + qbase + h * 16 + l16] =
            float2{-negM[h], lf};
      }
      _Float16* op = Opart + (size_t)split * tensElems + (size_t)bh * headElems;
      #pragma unroll
      for (int ri = 0; ri < 4; ++ri) {
        float lB = __shfl(linv, 4 * g + ri);
        const int row = qbase + h * 16 + 4 * g + ri;
        #pragma unroll
        for (int nt = 0; nt < 4; ++nt)
          op[(size_t)row * HDIM + nt * 16 + l16] = (_Float16)(acc[h][nt][ri] * lB);
      }
    } else {
      #pragma unroll
      for (int ri = 0; ri < 4; ++ri) {
        float lB = __shfl(linv, 4 * g + ri);
        const int row = qbase + h * 16 + 4 * g + ri;
        #pragma unroll
        for (int nt = 0; nt < 4; ++nt)
          O[(size_t)row * HDIM + nt * 16 + l16] = acc[h][nt][ri] * lB;
      }
    }
  }
}

extern "C" void kernel_launch(void* const* d_in, const int* in_sizes, int n_in,
                              void* d_out, int out_size, void* d_ws, size_t ws_size,
                              hipStream_t stream) {
  const float* QKV = (const float*)d_in[0];
  float* Out = (float*)d_out;
  const size_t tensElems = (size_t)NHEADS * SEQ * HDIM;             // 4,194,304
  const size_t k16Bytes = tensElems * sizeof(_Float16);             // 8.39 MB
  const size_t vtBytes = tensElems * sizeof(short);                 // 8.39 MB
  const size_t opBytes = (size_t)NSPLIT * tensElems * sizeof(_Float16);  // 16.78 MB
  const size_t mlBytes = (size_t)NSPLIT * NHEADS * SEQ * 8;         // 1.05 MB

  dim3 block(256);

  if (ws_size >= k16Bytes + vtBytes + opBytes + mlBytes) {
    _Float16* K16 = (_Float16*)d_ws;
    short* Vt16 = (short*)((char*)d_ws + k16Bytes);
    _Float16* Opart = (_Float16*)((char*)d_ws + k16Bytes + vtBytes);
    float2* Ml = (float2*)((char*)d_ws + k16Bytes + vtBytes + opBytes);
    hipLaunchKernelGGL(prep, dim3(3072), block, 0, stream, QKV, K16, Vt16);
    hipLaunchKernelGGL((flash_attn<true, true>), dim3(NHEADS * (SEQ / BR), NSPLIT),
                       block, 0, stream, QKV, K16, Vt16, Out, Opart, Ml);
    hipLaunchKernelGGL((combineN<NSPLIT>), dim3((NHEADS * SEQ * HDIM / 8) / 256),
                       block, 0, stream, Opart, Ml, Out);
  } else {
    hipLaunchKernelGGL((flash_attn<false, false>), dim3(NHEADS * (SEQ / BR)), block,
                       0, stream, QKV, (const _Float16*)nullptr,
                       (const short*)nullptr, Out, (_Float16*)nullptr,
                       (float2*)nullptr);
  }
}